// Round 1
// baseline (367.928 us; speedup 1.0000x reference)
//
#include <hip/hip_runtime.h>

#define N_FEAT 784
#define N_CLS  10

// Folded network: logits = x @ Weff^T + beff; out = softmax(logits).
// Weff/beff are recomputed per block into LDS (cheap: 7840 fused-FMA per block,
// inputs L2-resident), so no workspace is needed.
__global__ __launch_bounds__(256, 4) void sparse_fused_kernel(
    const float* __restrict__ x,
    const float* __restrict__ Wsp,   // [784,2]
    const float* __restrict__ bsp,   // [784,2]
    const float* __restrict__ fcw,   // [10,784]
    const float* __restrict__ fcb,   // [10]
    float* __restrict__ out)         // [65536,10]
{
    __shared__ float Wl[N_CLS * N_FEAT];   // folded weights, [10][784]
    __shared__ float bl[N_CLS];            // folded bias
    __shared__ float bred[4][N_CLS];

    const int tid  = threadIdx.x;
    const int lane = tid & 63;
    const int wave = tid >> 6;

    // ---- per-block fold of the sparse layer into fc ----
    float bacc[N_CLS];
#pragma unroll
    for (int n = 0; n < N_CLS; ++n) bacc[n] = 0.f;

    for (int i = tid; i < N_FEAT; i += 256) {
        // scatter map from the reference (incl. the i==782 wraparound bug)
        int c0 = (i == 782) ? 0 : i;
        int c1 = (i == 782) ? 1 : ((i == 783) ? 0 : (i + 1));
        float w0 = Wsp[2 * i], w1 = Wsp[2 * i + 1];
        float b0 = bsp[2 * i], b1 = bsp[2 * i + 1];
#pragma unroll
        for (int n = 0; n < N_CLS; ++n) {
            float f0 = fcw[n * N_FEAT + c0];
            float f1 = fcw[n * N_FEAT + c1];
            Wl[n * N_FEAT + i] = f0 * w0 + f1 * w1;
            bacc[n] += f0 * b0 + f1 * b1;
        }
    }
#pragma unroll
    for (int n = 0; n < N_CLS; ++n) {
#pragma unroll
        for (int d = 1; d < 64; d <<= 1)
            bacc[n] += __shfl_xor(bacc[n], d, 64);
    }
    if (lane == 0) {
#pragma unroll
        for (int n = 0; n < N_CLS; ++n) bred[wave][n] = bacc[n];
    }
    __syncthreads();
    if (tid < N_CLS)
        bl[tid] = bred[0][tid] + bred[1][tid] + bred[2][tid] + bred[3][tid] + fcb[tid];
    __syncthreads();

    // ---- main GEMM + softmax: each wave handles 4 rows per chunk, 4 chunks ----
    const float4* Wl4 = (const float4*)Wl;
    const int gw  = blockIdx.x * 4 + wave;   // global wave id, 0..4095
    const int sub = lane >> 4;               // row-within-chunk this lane handles in epilogue
    const int sl  = lane & 15;

    for (int c = 0; c < 4; ++c) {
        const int baseRow = gw * 16 + c * 4;
        const float4* xr0 = (const float4*)(x + (size_t)(baseRow + 0) * N_FEAT);
        const float4* xr1 = (const float4*)(x + (size_t)(baseRow + 1) * N_FEAT);
        const float4* xr2 = (const float4*)(x + (size_t)(baseRow + 2) * N_FEAT);
        const float4* xr3 = (const float4*)(x + (size_t)(baseRow + 3) * N_FEAT);

        float acc[N_CLS][4];
#pragma unroll
        for (int n = 0; n < N_CLS; ++n)
#pragma unroll
            for (int r = 0; r < 4; ++r) acc[n][r] = 0.f;

#pragma unroll
        for (int t = 0; t < 4; ++t) {
            int li = t * 64 + lane;          // float4 index into the row (0..195)
            if (li < N_FEAT / 4) {
                float4 x0 = xr0[li], x1 = xr1[li], x2 = xr2[li], x3 = xr3[li];
#pragma unroll
                for (int n = 0; n < N_CLS; ++n) {
                    float4 wv = Wl4[n * (N_FEAT / 4) + li];
                    acc[n][0] += wv.x * x0.x + wv.y * x0.y + wv.z * x0.z + wv.w * x0.w;
                    acc[n][1] += wv.x * x1.x + wv.y * x1.y + wv.z * x1.z + wv.w * x1.w;
                    acc[n][2] += wv.x * x2.x + wv.y * x2.y + wv.z * x2.z + wv.w * x2.w;
                    acc[n][3] += wv.x * x3.x + wv.y * x3.y + wv.z * x3.z + wv.w * x3.w;
                }
            }
        }

        // butterfly-reduce all 40 accumulators across the wave
#pragma unroll
        for (int d = 1; d < 64; d <<= 1) {
#pragma unroll
            for (int n = 0; n < N_CLS; ++n)
#pragma unroll
                for (int r = 0; r < 4; ++r)
                    acc[n][r] += __shfl_xor(acc[n][r], d, 64);
        }

        // fused softmax epilogue: 16-lane group g handles row baseRow+g
        float lg[N_CLS];
        float m = -1e30f;
#pragma unroll
        for (int n = 0; n < N_CLS; ++n) {
            float v = acc[n][0];
            v = (sub == 1) ? acc[n][1] : v;
            v = (sub == 2) ? acc[n][2] : v;
            v = (sub == 3) ? acc[n][3] : v;
            v += bl[n];
            lg[n] = v;
            m = fmaxf(m, v);
        }
        float den = 0.f;
#pragma unroll
        for (int n = 0; n < N_CLS; ++n) {
            float e = __expf(lg[n] - m);
            lg[n] = e;
            den += e;
        }
        float inv = 1.0f / den;
        float vout = lg[0];
#pragma unroll
        for (int n = 1; n < N_CLS; ++n) vout = (sl == n) ? lg[n] : vout;
        if (sl < N_CLS) {
            int row = baseRow + sub;
            out[(size_t)row * N_CLS + sl] = vout * inv;
        }
    }
}

extern "C" void kernel_launch(void* const* d_in, const int* in_sizes, int n_in,
                              void* d_out, int out_size, void* d_ws, size_t ws_size,
                              hipStream_t stream) {
    const float* x   = (const float*)d_in[0];   // [65536,784]
    const float* Wsp = (const float*)d_in[1];   // [784,2]
    const float* bsp = (const float*)d_in[2];   // [784,2]
    const float* fcw = (const float*)d_in[3];   // [10,784]
    const float* fcb = (const float*)d_in[4];   // [10]
    float* out = (float*)d_out;                 // [65536,10]

    // 1024 blocks x 256 threads: 4 waves/block, 16 rows/wave -> 65536 rows
    sparse_fused_kernel<<<1024, 256, 0, stream>>>(x, Wsp, bsp, fcw, fcb, out);
}

// Round 2
// 294.026 us; speedup vs baseline: 1.2513x; 1.2513x over previous
//
#include <hip/hip_runtime.h>

#define N_FEAT 784
#define NF4    196          // N_FEAT / 4
#define N_CLS  10

// Folded network: logits = x @ Weff^T + beff; out = softmax(logits).
// Weff/beff recomputed per block into LDS (7840 fused-FMA, inputs L2/L3-hot).
// Main loop: 16-lane group owns 2 rows; x read directly from global
// (coalesced 256B segments); Weff via conflict-free ds_read_b128 shared
// across both rows. Only 20 live accumulators/lane -> no spills.
__global__ __launch_bounds__(256, 4) void sparse_fused_kernel(
    const float* __restrict__ x,
    const float* __restrict__ Wsp,   // [784,2]
    const float* __restrict__ bsp,   // [784,2]
    const float* __restrict__ fcw,   // [10,784]
    const float* __restrict__ fcb,   // [10]
    float* __restrict__ out)         // [65536,10]
{
    __shared__ float Wl[N_CLS * N_FEAT];   // folded weights, [10][784]
    __shared__ float bl[N_CLS];            // folded bias
    __shared__ float bred[4][N_CLS];

    const int tid  = threadIdx.x;
    const int lane = tid & 63;
    const int wave = tid >> 6;

    // ---- per-block fold of the sparse layer into fc ----
    float bacc[N_CLS];
#pragma unroll
    for (int n = 0; n < N_CLS; ++n) bacc[n] = 0.f;

    for (int i = tid; i < N_FEAT; i += 256) {
        // scatter map from the reference (incl. the i==782 wraparound bug)
        int c0 = (i == 782) ? 0 : i;
        int c1 = (i == 782) ? 1 : ((i == 783) ? 0 : (i + 1));
        float w0 = Wsp[2 * i], w1 = Wsp[2 * i + 1];
        float b0 = bsp[2 * i], b1 = bsp[2 * i + 1];
#pragma unroll
        for (int n = 0; n < N_CLS; ++n) {
            float f0 = fcw[n * N_FEAT + c0];
            float f1 = fcw[n * N_FEAT + c1];
            Wl[n * N_FEAT + i] = f0 * w0 + f1 * w1;
            bacc[n] += f0 * b0 + f1 * b1;
        }
    }
#pragma unroll
    for (int n = 0; n < N_CLS; ++n) {
#pragma unroll
        for (int d = 1; d < 64; d <<= 1)
            bacc[n] += __shfl_xor(bacc[n], d, 64);
    }
    if (lane == 0) {
#pragma unroll
        for (int n = 0; n < N_CLS; ++n) bred[wave][n] = bacc[n];
    }
    __syncthreads();
    if (tid < N_CLS)
        bl[tid] = bred[0][tid] + bred[1][tid] + bred[2][tid] + bred[3][tid] + fcb[tid];
    __syncthreads();

    // ---- main GEMM + softmax ----
    const float4* Wl4 = (const float4*)Wl;
    const int gw = blockIdx.x * 4 + wave;   // global wave id, 0..4095
    const int g  = lane >> 4;               // 16-lane group, 0..3
    const int sl = lane & 15;

#pragma unroll
    for (int pass = 0; pass < 2; ++pass) {
        // each wave-pass covers 8 rows: group g owns rows rbase, rbase+1
        const int rbase = (gw * 2 + pass) * 8 + g * 2;
        const float4* xr0 = (const float4*)(x + (size_t)rbase * N_FEAT);
        const float4* xr1 = (const float4*)(x + (size_t)(rbase + 1) * N_FEAT);

        float acc0[N_CLS], acc1[N_CLS];
#pragma unroll
        for (int n = 0; n < N_CLS; ++n) { acc0[n] = 0.f; acc1[n] = 0.f; }

        // lanes stride the 196 float4 features; 12 full steps + tail (sl<4)
        for (int k4 = sl; k4 < NF4; k4 += 16) {
            float4 x0 = xr0[k4];
            float4 x1 = xr1[k4];
#pragma unroll
            for (int n = 0; n < N_CLS; ++n) {
                float4 wv = Wl4[n * NF4 + k4];
                acc0[n] += wv.x * x0.x + wv.y * x0.y + wv.z * x0.z + wv.w * x0.w;
                acc1[n] += wv.x * x1.x + wv.y * x1.y + wv.z * x1.z + wv.w * x1.w;
            }
        }

        // intra-group (16-lane) butterfly; all 4 groups reduce in parallel
#pragma unroll
        for (int d = 1; d < 16; d <<= 1) {
#pragma unroll
            for (int n = 0; n < N_CLS; ++n) {
                acc0[n] += __shfl_xor(acc0[n], d, 64);
                acc1[n] += __shfl_xor(acc1[n], d, 64);
            }
        }

        // fused softmax for both rows (computed redundantly in all 16 lanes)
        float m0 = -1e30f, m1 = -1e30f;
#pragma unroll
        for (int n = 0; n < N_CLS; ++n) {
            acc0[n] += bl[n];
            acc1[n] += bl[n];
            m0 = fmaxf(m0, acc0[n]);
            m1 = fmaxf(m1, acc1[n]);
        }
        float den0 = 0.f, den1 = 0.f;
#pragma unroll
        for (int n = 0; n < N_CLS; ++n) {
            acc0[n] = __expf(acc0[n] - m0);
            acc1[n] = __expf(acc1[n] - m1);
            den0 += acc0[n];
            den1 += acc1[n];
        }
        float inv0 = 1.0f / den0, inv1 = 1.0f / den1;
        float v0 = acc0[0], v1 = acc1[0];
#pragma unroll
        for (int n = 1; n < N_CLS; ++n) {
            v0 = (sl == n) ? acc0[n] : v0;
            v1 = (sl == n) ? acc1[n] : v1;
        }
        if (sl < N_CLS) {
            out[(size_t)rbase * N_CLS + sl]       = v0 * inv0;
            out[(size_t)(rbase + 1) * N_CLS + sl] = v1 * inv1;
        }
    }
}

extern "C" void kernel_launch(void* const* d_in, const int* in_sizes, int n_in,
                              void* d_out, int out_size, void* d_ws, size_t ws_size,
                              hipStream_t stream) {
    const float* x   = (const float*)d_in[0];   // [65536,784]
    const float* Wsp = (const float*)d_in[1];   // [784,2]
    const float* bsp = (const float*)d_in[2];   // [784,2]
    const float* fcw = (const float*)d_in[3];   // [10,784]
    const float* fcb = (const float*)d_in[4];   // [10]
    float* out = (float*)d_out;                 // [65536,10]

    // 1024 blocks x 256 threads: 4 waves/block, 2 passes x 8 rows per wave
    sparse_fused_kernel<<<1024, 256, 0, stream>>>(x, Wsp, bsp, fcw, fcb, out);
}